// Round 3
// baseline (903.641 us; speedup 1.0000x reference)
//
#include <hip/hip_runtime.h>
#include <hip/hip_cooperative_groups.h>
#include <hip/hip_bf16.h>
#include <stdint.h>

namespace cg = cooperative_groups;

#define N_TOK 4096
#define C_DIM 1024
#define H_DIM 2048
#define V_DIM 32000
#define NE_MLP 8
#define NE_TOT 10

typedef __attribute__((ext_vector_type(8))) short bf16x8;
typedef __attribute__((ext_vector_type(4))) short bf16x4;
typedef __attribute__((ext_vector_type(4))) float f32x4;

#define BM 128
#define BN 128
#define BND 64
#define HKE 32                  // elems per half-K
#define HALF_ELEMS (128 * 32)   // one 128-row x 32-col bf16 image
#define HALF_B (64 * 32)        // one 64-row x 32-col bf16 image (down B)
#define CVT_W (NE_MLP * H_DIM * C_DIM / 4)

__device__ __forceinline__ void gload16(const void* g, void* l) {
    __builtin_amdgcn_global_load_lds(
        (const __attribute__((address_space(1))) void*)g,
        (__attribute__((address_space(3))) void*)l,
        16, 0, 0);
}

__device__ __forceinline__ unsigned short bf16bits(float v) {
    __hip_bfloat16 h = __float2bfloat16(v);
    return *reinterpret_cast<unsigned short*>(&h);
}

struct MegaParams {
    const float* x;
    const int*   tok_ids;
    const float* wu;
    const float* wd;
    const float* rw;
    const float* rb;
    const float* vt;
    __hip_bfloat16* xb;
    __hip_bfloat16* wub;
    __hip_bfloat16* wdb;
    int*   tok_list;
    float* wlist;
    int*   cnt;
    __hip_bfloat16* hidden;
    float* out;
};

// ---------------- phase 0a: router + fused x->bf16 + ve-init ----------------
__device__ __forceinline__ void router_quad(const MegaParams& p, int q)
{
    const int lane = threadIdx.x & 63;
    const int n = q * 4 + (threadIdx.x >> 6);
    const f32x4* xr  = reinterpret_cast<const f32x4*>(p.x + (size_t)n * C_DIM);
    const f32x4* rw4 = reinterpret_cast<const f32x4*>(p.rw);
    bf16x4* xbr = reinterpret_cast<bf16x4*>(p.xb + (size_t)n * C_DIM);

    float acc[NE_TOT];
    #pragma unroll
    for (int e = 0; e < NE_TOT; ++e) acc[e] = 0.f;

    #pragma unroll
    for (int kk = 0; kk < C_DIM / 256; ++kk) {
        f32x4 xv = xr[kk * 64 + lane];
        bf16x4 xbv;
        xbv.x = (short)bf16bits(xv.x); xbv.y = (short)bf16bits(xv.y);
        xbv.z = (short)bf16bits(xv.z); xbv.w = (short)bf16bits(xv.w);
        xbr[kk * 64 + lane] = xbv;
        #pragma unroll
        for (int e = 0; e < NE_TOT; ++e) {
            f32x4 wv = rw4[e * (C_DIM / 4) + kk * 64 + lane];
            acc[e] += xv.x * wv.x + xv.y * wv.y + xv.z * wv.z + xv.w * wv.w;
        }
    }
    #pragma unroll
    for (int e = 0; e < NE_TOT; ++e) {
        for (int m = 32; m > 0; m >>= 1) acc[e] += __shfl_xor(acc[e], m, 64);
    }

    float wv0 = 0.f, wv1 = 0.f;
    if (lane == 0) {
        float s[NE_TOT], sb[NE_TOT];
        #pragma unroll
        for (int e = 0; e < NE_TOT; ++e) {
            s[e]  = 1.f / (1.f + expf(-acc[e]));
            sb[e] = s[e] + p.rb[e];
        }
        int i0 = 0;
        #pragma unroll
        for (int e = 1; e < NE_TOT; ++e) if (sb[e] > sb[i0]) i0 = e;
        int i1 = (i0 == 0) ? 1 : 0;
        #pragma unroll
        for (int e = 0; e < NE_TOT; ++e)
            if (e != i0 && sb[e] > sb[i1]) i1 = e;

        float w0 = s[i0], w1 = s[i1];
        float inv = 1.f / (w0 + w1);
        w0 *= inv; w1 *= inv;

        int   idx[2] = {i0, i1};
        float wt[2]  = {w0, w1};
        #pragma unroll
        for (int k = 0; k < 2; ++k) {
            if (idx[k] < NE_MLP) {
                int pidx = atomicAdd(&p.cnt[idx[k]], 1);
                p.tok_list[idx[k] * N_TOK + pidx] = n;
                p.wlist[idx[k] * N_TOK + pidx] = wt[k];
            } else {
                if (idx[k] == NE_MLP) wv0 = wt[k]; else wv1 = wt[k];
            }
        }
    }
    wv0 = __shfl(wv0, 0, 64);
    wv1 = __shfl(wv1, 0, 64);
    const int t = p.tok_ids[n];
    const f32x4* v0 = reinterpret_cast<const f32x4*>(p.vt + (size_t)t * C_DIM);
    const f32x4* v1 = reinterpret_cast<const f32x4*>(p.vt + ((size_t)V_DIM + t) * C_DIM);
    f32x4* orow = reinterpret_cast<f32x4*>(p.out + (size_t)n * C_DIM);
    #pragma unroll
    for (int qq = 0; qq < 4; ++qq) {
        const int c = qq * 64 + lane;
        f32x4 v = {0.f, 0.f, 0.f, 0.f};
        if (wv0 != 0.f) v += wv0 * v0[c];
        if (wv1 != 0.f) v += wv1 * v1[c];
        orow[c] = v;
    }
}

// ---------------- phase 1 tile: hidden = relu(x @ w_up^T)^2 ----------------
__device__ __forceinline__ void up_tile(
    const MegaParams& p, int e, int count, int m0, int n0,
    __hip_bfloat16* lA, __hip_bfloat16* lB)
{
    const int tid  = threadIdx.x;
    const int lane = tid & 63;
    const int wv   = tid >> 6;
    const int wm = (wv >> 1) * 64;
    const int wn = (wv & 1) * 64;

    const __hip_bfloat16* ga[2];
    const __hip_bfloat16* gb[2];
    __hip_bfloat16* la[2];
    __hip_bfloat16* lb[2];
    const __hip_bfloat16* wB = p.wub + (size_t)e * H_DIM * C_DIM;
    #pragma unroll
    for (int t = 0; t < 2; ++t) {
        const int srow = (wv + 4 * t) * 16 + (lane >> 2);
        int r = m0 + srow;
        const int tok = p.tok_list[e * N_TOK + (r < count ? r : count - 1)];
        ga[t] = p.xb + (size_t)tok * C_DIM + (lane & 3) * 8;
        gb[t] = wB + (size_t)(n0 + srow) * C_DIM + (lane & 3) * 8;
        la[t] = lA + (wv + 4 * t) * 512;
        lb[t] = lB + (wv + 4 * t) * 512;
    }

    f32x4 acc[4][4];
    #pragma unroll
    for (int i = 0; i < 4; ++i)
        #pragma unroll
        for (int j = 0; j < 4; ++j)
            acc[i][j] = (f32x4){0.f, 0.f, 0.f, 0.f};

    const int fm  = lane & 15;
    const int fkb = (lane >> 4) * 8;

    for (int k0 = 0; k0 < C_DIM; k0 += 2 * HKE) {
        __syncthreads();
        #pragma unroll
        for (int h = 0; h < 2; ++h) {
            #pragma unroll
            for (int t = 0; t < 2; ++t) {
                gload16(ga[t] + h * HKE, la[t] + h * HALF_ELEMS);
                gload16(gb[t] + h * HKE, lb[t] + h * HALF_ELEMS);
            }
        }
        #pragma unroll
        for (int t = 0; t < 2; ++t) { ga[t] += 2 * HKE; gb[t] += 2 * HKE; }
        __syncthreads();
        #pragma unroll
        for (int h = 0; h < 2; ++h) {
            bf16x8 af[4], bfr[4];
            #pragma unroll
            for (int i = 0; i < 4; ++i) {
                af[i]  = *reinterpret_cast<const bf16x8*>(lA + h * HALF_ELEMS + (wm + i * 16 + fm) * HKE + fkb);
                bfr[i] = *reinterpret_cast<const bf16x8*>(lB + h * HALF_ELEMS + (wn + i * 16 + fm) * HKE + fkb);
            }
            #pragma unroll
            for (int i = 0; i < 4; ++i)
                #pragma unroll
                for (int j = 0; j < 4; ++j)
                    acc[i][j] = __builtin_amdgcn_mfma_f32_16x16x32_bf16(af[i], bfr[j], acc[i][j], 0, 0, 0);
        }
    }

    const int fr = (lane >> 4) * 4;
    #pragma unroll
    for (int i = 0; i < 4; ++i) {
        #pragma unroll
        for (int r = 0; r < 4; ++r) {
            const int gr = m0 + wm + i * 16 + fr + r;
            const bool ok = gr < count;
            unsigned int pk[4];
            #pragma unroll
            for (int j = 0; j < 4; ++j) {
                float v = acc[i][j][r];
                v = v > 0.f ? v * v : 0.f;
                unsigned short b = bf16bits(v);
                int other = __shfl_xor((int)b, 1, 64);
                pk[j] = (unsigned)b | ((unsigned)other << 16);
            }
            if (ok && !(lane & 1)) {
                __hip_bfloat16* hrow = p.hidden + (size_t)(e * N_TOK + gr) * H_DIM + n0 + wn + fm;
                #pragma unroll
                for (int j = 0; j < 4; ++j)
                    *reinterpret_cast<unsigned int*>(hrow + j * 16) = pk[j];
            }
        }
    }
}

// --------- phase 2 tile (full K=2048, BN=64): out += w * (h @ w_down^T) ----
__device__ __forceinline__ void down_tile(
    const MegaParams& p, int e, int count, int m0, int n0,
    __hip_bfloat16* lA, __hip_bfloat16* lB)
{
    const int tid  = threadIdx.x;
    const int lane = tid & 63;
    const int wv   = tid >> 6;
    const int wm = (wv >> 1) * 64;
    const int wn = (wv & 1) * 32;

    const __hip_bfloat16* ga[2];
    __hip_bfloat16* la[2];
    #pragma unroll
    for (int t = 0; t < 2; ++t) {
        const int srow = (wv + 4 * t) * 16 + (lane >> 2);
        int r = m0 + srow;
        const int arow = e * N_TOK + (r < count ? r : count - 1);
        ga[t] = p.hidden + (size_t)arow * H_DIM + (lane & 3) * 8;
        la[t] = lA + (wv + 4 * t) * 512;
    }
    const int srowB = wv * 16 + (lane >> 2);
    const __hip_bfloat16* gb = p.wdb + (size_t)e * C_DIM * H_DIM
                             + (size_t)(n0 + srowB) * H_DIM + (lane & 3) * 8;
    __hip_bfloat16* lb = lB + wv * 512;

    f32x4 acc[4][2];
    #pragma unroll
    for (int i = 0; i < 4; ++i)
        #pragma unroll
        for (int j = 0; j < 2; ++j)
            acc[i][j] = (f32x4){0.f, 0.f, 0.f, 0.f};

    const int fm  = lane & 15;
    const int fkb = (lane >> 4) * 8;

    for (int k0 = 0; k0 < H_DIM; k0 += 2 * HKE) {
        __syncthreads();
        #pragma unroll
        for (int h = 0; h < 2; ++h) {
            #pragma unroll
            for (int t = 0; t < 2; ++t)
                gload16(ga[t] + h * HKE, la[t] + h * HALF_ELEMS);
            gload16(gb + h * HKE, lb + h * HALF_B);
        }
        #pragma unroll
        for (int t = 0; t < 2; ++t) ga[t] += 2 * HKE;
        gb += 2 * HKE;
        __syncthreads();
        #pragma unroll
        for (int h = 0; h < 2; ++h) {
            bf16x8 af[4], bfr[2];
            #pragma unroll
            for (int i = 0; i < 4; ++i)
                af[i]  = *reinterpret_cast<const bf16x8*>(lA + h * HALF_ELEMS + (wm + i * 16 + fm) * HKE + fkb);
            #pragma unroll
            for (int j = 0; j < 2; ++j)
                bfr[j] = *reinterpret_cast<const bf16x8*>(lB + h * HALF_B + (wn + j * 16 + fm) * HKE + fkb);
            #pragma unroll
            for (int i = 0; i < 4; ++i)
                #pragma unroll
                for (int j = 0; j < 2; ++j)
                    acc[i][j] = __builtin_amdgcn_mfma_f32_16x16x32_bf16(af[i], bfr[j], acc[i][j], 0, 0, 0);
        }
    }

    const int fr = (lane >> 4) * 4;
    #pragma unroll
    for (int i = 0; i < 4; ++i) {
        #pragma unroll
        for (int r = 0; r < 4; ++r) {
            const int gr = m0 + wm + i * 16 + fr + r;
            if (gr < count) {
                const int   tok = p.tok_list[e * N_TOK + gr];
                const float w   = p.wlist[e * N_TOK + gr];
                float* orow = p.out + (size_t)tok * C_DIM + n0 + wn + fm;
                #pragma unroll
                for (int j = 0; j < 2; ++j)
                    __hip_atomic_fetch_add(orow + j * 16, w * acc[i][j][r],
                                           __ATOMIC_RELAXED, __HIP_MEMORY_SCOPE_AGENT);
            }
        }
    }
}

// ------------------------------ mega kernel --------------------------------
__global__ void __launch_bounds__(256, 4) mega_kernel(MegaParams p)
{
    __shared__ __hip_bfloat16 lA[2 * HALF_ELEMS];
    __shared__ __hip_bfloat16 lB[2 * HALF_ELEMS];

    const int bid = blockIdx.x;
    const int G   = gridDim.x;

    // ---- phase 0: router (+x cvt, ve-init) and weight cvt ----
    for (int q = bid; q < N_TOK / 4; q += G)
        router_quad(p, q);

    for (int j = bid * 256 + (int)threadIdx.x; j < 2 * CVT_W; j += G * 256) {
        const float* src;
        __hip_bfloat16* dst;
        int jj;
        if (j < CVT_W) { src = p.wu; dst = p.wub; jj = j; }
        else           { src = p.wd; dst = p.wdb; jj = j - CVT_W; }
        f32x4 v = reinterpret_cast<const f32x4*>(src)[jj];
        bf16x4 b;
        b.x = (short)bf16bits(v.x); b.y = (short)bf16bits(v.y);
        b.z = (short)bf16bits(v.z); b.w = (short)bf16bits(v.w);
        reinterpret_cast<bf16x4*>(dst)[jj] = b;
    }

    __threadfence();
    cg::this_grid().sync();

    // ---- tile bookkeeping from final counts ----
    int cnts[NE_MLP];
    int pre[NE_MLP + 1];
    pre[0] = 0;
    #pragma unroll
    for (int e = 0; e < NE_MLP; ++e) {
        cnts[e] = p.cnt[e];
        pre[e + 1] = pre[e] + ((cnts[e] + BM - 1) >> 7);
    }
    const int nMB = pre[NE_MLP];

    // ---- phase 1: up-proj, 16 n-tiles (BN=128) per active m-tile ----
    for (int t = bid; t < nMB * 16; t += G) {
        const int em = t >> 4, nx = t & 15;
        int e = 0;
        while (em >= pre[e + 1]) ++e;
        up_tile(p, e, cnts[e], (em - pre[e]) * BM, nx * BN, lA, lB);
    }

    __threadfence();
    cg::this_grid().sync();

    // ---- phase 2: down-proj, 16 n-tiles (BND=64) per active m-tile ----
    for (int t = bid; t < nMB * 16; t += G) {
        const int em = t >> 4, nx = t & 15;
        int e = 0;
        while (em >= pre[e + 1]) ++e;
        down_tile(p, e, cnts[e], (em - pre[e]) * BM, nx * BND, lA, lB);
    }
}

extern "C" void kernel_launch(void* const* d_in, const int* in_sizes, int n_in,
                              void* d_out, int out_size, void* d_ws, size_t ws_size,
                              hipStream_t stream)
{
    const float* x         = (const float*)d_in[0];
    const int*   token_ids = (const int*)  d_in[1];
    const float* w_up      = (const float*)d_in[2];
    const float* w_down    = (const float*)d_in[3];
    const float* router_w  = (const float*)d_in[4];
    const float* router_b  = (const float*)d_in[5];
    const float* ve_tables = (const float*)d_in[6];
    float* out = (float*)d_out;

    char* ws = (char*)d_ws;
    size_t off = 0;
    __hip_bfloat16* hidden  = (__hip_bfloat16*)(ws + off); off += (size_t)NE_MLP * N_TOK * H_DIM * 2;  // 134 MB
    __hip_bfloat16* xb      = (__hip_bfloat16*)(ws + off); off += (size_t)N_TOK * C_DIM * 2;
    __hip_bfloat16* wub     = (__hip_bfloat16*)(ws + off); off += (size_t)NE_MLP * H_DIM * C_DIM * 2;
    __hip_bfloat16* wdb     = (__hip_bfloat16*)(ws + off); off += (size_t)NE_MLP * C_DIM * H_DIM * 2;
    int*   tok_list = (int*)  (ws + off); off += (size_t)NE_MLP * N_TOK * 4;
    float* wlist    = (float*)(ws + off); off += (size_t)NE_MLP * N_TOK * 4;
    int*   cnt      = (int*)  (ws + off); off += 64;

    hipMemsetAsync(cnt, 0, NE_MLP * sizeof(int), stream);

    MegaParams p;
    p.x = x; p.tok_ids = token_ids; p.wu = w_up; p.wd = w_down;
    p.rw = router_w; p.rb = router_b; p.vt = ve_tables;
    p.xb = xb; p.wub = wub; p.wdb = wdb;
    p.tok_list = tok_list; p.wlist = wlist; p.cnt = cnt;
    p.hidden = hidden; p.out = out;

    // clamp grid to guaranteed co-residency for the cooperative launch
    static int maxb = -1;
    if (maxb < 0) {
        hipOccupancyMaxActiveBlocksPerMultiprocessor(&maxb, mega_kernel, 256, 0);
        if (maxb < 1) maxb = 1;
    }
    int grid = maxb * 256;
    if (grid > 1024) grid = 1024;

    void* kargs[] = { (void*)&p };
    hipLaunchCooperativeKernel((void*)mega_kernel, dim3(grid), dim3(256),
                               kargs, 0, stream);
}